// Round 7
// baseline (34836.581 us; speedup 1.0000x reference)
//
#include <hip/hip_runtime.h>
#include <cstdint>

#define T_STEPS 8192
#define HDIM    1024
#define NBLK    256
#define NTHR    256

typedef float        f32x4 __attribute__((ext_vector_type(4)));
typedef unsigned int u32x4 __attribute__((ext_vector_type(4)));

__device__ __forceinline__ float dot4(f32x4 a, f32x4 b) {
    return a[0] * b[0] + a[1] * b[1] + a[2] * b[2] + a[3] * b[3];
}
__device__ __forceinline__ float sigmoidf_(float v) { return 1.0f / (1.0f + __expf(-v)); }
__device__ __forceinline__ float tanhf_(float v)    { return 1.0f - 2.0f / (__expf(2.0f * v) + 1.0f); }
__device__ __forceinline__ unsigned bf16_rne(float f) {
    unsigned b = __float_as_uint(f);
    return (b + 0x7FFFu + ((b >> 16) & 1u)) >> 16;   // round-nearest-even
}

// R3's proven fused structure. ONLY the handoff payload changed:
// ring entry = u32 packing (epoch16 << 16) | bf16(h). Poll = ONE dwordx4
// (16B, 4 units) per thread instead of 2x dwordx4 (32B) — halves the
// GPU-wide spin traffic (~6 TB/s at the IF$ in R3) that was congesting
// the publish/detect path. bf16 only on the recurrent handoff; out[] and
// all arithmetic stay f32.
__global__ __launch_bounds__(NTHR, 1)
void lstm_persistent(const float* __restrict__ x,
                     const float* __restrict__ W_ih,
                     const float* __restrict__ W_hh,
                     const float* __restrict__ b_ih,
                     const float* __restrict__ b_hh,
                     const float* __restrict__ h0,
                     const float* __restrict__ c0,
                     float* __restrict__ out,
                     unsigned int* __restrict__ ring)
{
    __shared__ float h_lds[2][HDIM];

    const int tid = threadIdx.x;
    const int w   = tid >> 6;   // wave 0..3
    const int l   = tid & 63;   // lane
    const int u   = (blockIdx.x << 2) + w;

    // ---- weights: lane l covers elements 4l + 256i (+j) ----
    f32x4 whh[16], wih[16];
#pragma unroll
    for (int q = 0; q < 4; ++q) {
        const float* rh = W_hh + (size_t)(q * HDIM + u) * HDIM + 4 * l;
        const float* ri = W_ih + (size_t)(q * HDIM + u) * HDIM + 4 * l;
#pragma unroll
        for (int i = 0; i < 4; ++i) {
            whh[q * 4 + i] = *(const f32x4*)(rh + 256 * i);
            wih[q * 4 + i] = *(const f32x4*)(ri + 256 * i);
        }
    }
#pragma unroll
    for (int k = 0; k < 16; ++k) {
        asm volatile("" : "+v"(whh[k]));
        asm volatile("" : "+v"(wih[k]));
    }

    float bias[4];
#pragma unroll
    for (int q = 0; q < 4; ++q) bias[q] = b_ih[q * HDIM + u] + b_hh[q * HDIM + u];
    float c = c0[u];  // replicated across the wave

    f32x4 hr[4];
#pragma unroll
    for (int i = 0; i < 4; ++i) hr[i] = *(const f32x4*)(h0 + 4 * l + 256 * i);

    // x pipeline: gxp = Wih partials for step t; xr = x[t+1]; xn = x[t+2]
    float gxp[4];
    {
        f32x4 x0[4];
#pragma unroll
        for (int i = 0; i < 4; ++i) x0[i] = *(const f32x4*)(x + 4 * l + 256 * i);
#pragma unroll
        for (int q = 0; q < 4; ++q) {
            float a = 0.f;
#pragma unroll
            for (int i = 0; i < 4; ++i) a += dot4(wih[q * 4 + i], x0[i]);
            gxp[q] = a;
        }
    }
    f32x4 xr[4], xn[4];
#pragma unroll
    for (int i = 0; i < 4; ++i) xr[i] = *(const f32x4*)(x + HDIM + 4 * l + 256 * i);

    for (int t = 0; t < T_STEPS; ++t) {
        // gates = gxp + Whh . h_{t-1}
        float acc[4];
#pragma unroll
        for (int q = 0; q < 4; ++q) {
            float a = gxp[q];
#pragma unroll
            for (int i = 0; i < 4; ++i) a += dot4(whh[q * 4 + i], hr[i]);
            acc[q] = a;
        }
#pragma unroll
        for (int m = 1; m < 64; m <<= 1) {
#pragma unroll
            for (int q = 0; q < 4; ++q) acc[q] += __shfl_xor(acc[q], m, 64);
        }
        const float gi = sigmoidf_(acc[0] + bias[0]);
        const float gf = sigmoidf_(acc[1] + bias[1]);
        const float gg = tanhf_   (acc[2] + bias[2]);
        const float go = sigmoidf_(acc[3] + bias[3]);
        c = gf * c + gi * gg;
        const float hval = go * tanhf_(c);   // identical on all 64 lanes

        if (l == 0) {
            // publish: 4B packed (epoch|bf16) system-scope store
            const unsigned pk = ((unsigned)(t + 1) << 16) | bf16_rne(hval);
            asm volatile("global_store_dword %0, %1, off sc0 sc1"
                         :: "v"((unsigned long long)&ring[(t & 1) * HDIM + u]),
                            "v"(pk) : "memory");
        }
        if (l == 1) out[(size_t)t * HDIM + u] = hval;   // off the publish path
        if (t == T_STEPS - 1) break;

        // x[t+2] prefetch (latency absorbed by the poll's vmcnt once)
        {
            const int tn = (t + 2 < T_STEPS) ? (t + 2) : (T_STEPS - 1);
            const float* xp = x + (size_t)tn * HDIM;
#pragma unroll
            for (int i = 0; i < 4; ++i) xn[i] = *(const f32x4*)(xp + 4 * l + 256 * i);
        }
        // gx partials for step t+1 (independent of h_t)
#pragma unroll
        for (int q = 0; q < 4; ++q) {
            float a = 0.f;
#pragma unroll
            for (int i = 0; i < 4; ++i) a += dot4(wih[q * 4 + i], xr[i]);
            gxp[q] = a;
        }

        // wait for h_t: ONE 16B system-scope read per poll (4 units/thread)
        {
            const unsigned e = (unsigned)(t + 1);
            const unsigned long long base =
                (unsigned long long)(ring + (t & 1) * HDIM + 4 * tid);
            u32x4 p;
            for (;;) {
                asm volatile(
                    "global_load_dwordx4 %0, %1, off sc0 sc1\n\t"
                    "s_waitcnt vmcnt(0)"
                    : "=&v"(p)
                    : "v"(base)
                    : "memory");
                if ((p[0] >> 16) == e && (p[1] >> 16) == e &&
                    (p[2] >> 16) == e && (p[3] >> 16) == e) break;
            }
            const int ns = (t + 1) & 1;
            f32x4 hv;
            hv[0] = __uint_as_float(p[0] << 16);
            hv[1] = __uint_as_float(p[1] << 16);
            hv[2] = __uint_as_float(p[2] << 16);
            hv[3] = __uint_as_float(p[3] << 16);
            *(f32x4*)&h_lds[ns][4 * tid] = hv;
        }
        __syncthreads();
        {
            const int ns = (t + 1) & 1;
#pragma unroll
            for (int i = 0; i < 4; ++i)
                hr[i] = *(const f32x4*)&h_lds[ns][4 * l + 256 * i];
        }
#pragma unroll
        for (int i = 0; i < 4; ++i) xr[i] = xn[i];
    }
}

extern "C" void kernel_launch(void* const* d_in, const int* in_sizes, int n_in,
                              void* d_out, int out_size, void* d_ws, size_t ws_size,
                              hipStream_t stream)
{
    const float* x    = (const float*)d_in[0];
    const float* W_ih = (const float*)d_in[1];
    const float* W_hh = (const float*)d_in[2];
    const float* b_ih = (const float*)d_in[3];
    const float* b_hh = (const float*)d_in[4];
    const float* h0   = (const float*)d_in[5];
    const float* c0   = (const float*)d_in[6];

    unsigned int* ring = (unsigned int*)d_ws;
    hipMemsetAsync(d_ws, 0, 2 * HDIM * sizeof(unsigned int), stream);
    lstm_persistent<<<NBLK, NTHR, 0, stream>>>(x, W_ih, W_hh, b_ih, b_hh, h0, c0,
                                               (float*)d_out, ring);
}

// Round 8
// 22267.699 us; speedup vs baseline: 1.5644x; 1.5644x over previous
//
#include <hip/hip_runtime.h>
#include <cstdint>

#define T_STEPS 8192
#define HDIM    1024
#define NBLK    256
#define NTHR    256

typedef float        f32x4 __attribute__((ext_vector_type(4)));
typedef unsigned int u32x4 __attribute__((ext_vector_type(4)));

__device__ __forceinline__ float dot4(f32x4 a, f32x4 b) {
    return a[0] * b[0] + a[1] * b[1] + a[2] * b[2] + a[3] * b[3];
}
__device__ __forceinline__ float sigmoidf_(float v) { return 1.0f / (1.0f + __expf(-v)); }
__device__ __forceinline__ float tanhf_(float v)    { return 1.0f - 2.0f / (__expf(2.0f * v) + 1.0f); }
__device__ __forceinline__ unsigned bf16_rne(float f) {
    unsigned b = __float_as_uint(f);
    return (b + 0x7FFFu + ((b >> 16) & 1u)) >> 16;   // round-nearest-even
}

// R3's proven fused structure; ONLY the ring layout changed.
// Ring: u32 [2][NBLK][16] — ONE 64B line per publisher block per parity.
// Cross-round evidence: writers-per-line 2 (R1/R3/R5: 23.4-25.8ms) vs 4
// (R7: 34.8ms) — cross-CU stores to a shared line serialize at the
// coherence point. Here each line has ONE writer CU (4 lane-0 stores from
// the same CU at offsets w*4B), and poller thread tid reads exactly block
// tid's 16B (its 4 units) in one dwordx4. Payload: (epoch16<<16)|bf16(h),
// epoch per u32 so partial line visibility is safe (R7 validated bf16
// handoff precision: absmax 3.9e-3 << 14.1e-3).
__global__ __launch_bounds__(NTHR, 1)
void lstm_persistent(const float* __restrict__ x,
                     const float* __restrict__ W_ih,
                     const float* __restrict__ W_hh,
                     const float* __restrict__ b_ih,
                     const float* __restrict__ b_hh,
                     const float* __restrict__ h0,
                     const float* __restrict__ c0,
                     float* __restrict__ out,
                     unsigned int* __restrict__ ring)
{
    __shared__ float h_lds[2][HDIM];

    const int tid = threadIdx.x;
    const int w   = tid >> 6;   // wave 0..3
    const int l   = tid & 63;   // lane
    const int u   = (blockIdx.x << 2) + w;

    // ---- weights: lane l covers elements 4l + 256i (+j) ----
    f32x4 whh[16], wih[16];
#pragma unroll
    for (int q = 0; q < 4; ++q) {
        const float* rh = W_hh + (size_t)(q * HDIM + u) * HDIM + 4 * l;
        const float* ri = W_ih + (size_t)(q * HDIM + u) * HDIM + 4 * l;
#pragma unroll
        for (int i = 0; i < 4; ++i) {
            whh[q * 4 + i] = *(const f32x4*)(rh + 256 * i);
            wih[q * 4 + i] = *(const f32x4*)(ri + 256 * i);
        }
    }
#pragma unroll
    for (int k = 0; k < 16; ++k) {
        asm volatile("" : "+v"(whh[k]));
        asm volatile("" : "+v"(wih[k]));
    }

    float bias[4];
#pragma unroll
    for (int q = 0; q < 4; ++q) bias[q] = b_ih[q * HDIM + u] + b_hh[q * HDIM + u];
    float c = c0[u];  // replicated across the wave

    f32x4 hr[4];
#pragma unroll
    for (int i = 0; i < 4; ++i) hr[i] = *(const f32x4*)(h0 + 4 * l + 256 * i);

    // x pipeline: gxp = Wih partials for step t; xr = x[t+1]; xn = x[t+2]
    float gxp[4];
    {
        f32x4 x0[4];
#pragma unroll
        for (int i = 0; i < 4; ++i) x0[i] = *(const f32x4*)(x + 4 * l + 256 * i);
#pragma unroll
        for (int q = 0; q < 4; ++q) {
            float a = 0.f;
#pragma unroll
            for (int i = 0; i < 4; ++i) a += dot4(wih[q * 4 + i], x0[i]);
            gxp[q] = a;
        }
    }
    f32x4 xr[4], xn[4];
#pragma unroll
    for (int i = 0; i < 4; ++i) xr[i] = *(const f32x4*)(x + HDIM + 4 * l + 256 * i);

    for (int t = 0; t < T_STEPS; ++t) {
        // gates = gxp + Whh . h_{t-1}
        float acc[4];
#pragma unroll
        for (int q = 0; q < 4; ++q) {
            float a = gxp[q];
#pragma unroll
            for (int i = 0; i < 4; ++i) a += dot4(whh[q * 4 + i], hr[i]);
            acc[q] = a;
        }
#pragma unroll
        for (int m = 1; m < 64; m <<= 1) {
#pragma unroll
            for (int q = 0; q < 4; ++q) acc[q] += __shfl_xor(acc[q], m, 64);
        }
        const float gi = sigmoidf_(acc[0] + bias[0]);
        const float gf = sigmoidf_(acc[1] + bias[1]);
        const float gg = tanhf_   (acc[2] + bias[2]);
        const float go = sigmoidf_(acc[3] + bias[3]);
        c = gf * c + gi * gg;
        const float hval = go * tanhf_(c);   // identical on all 64 lanes

        if (l == 0) {
            // publish into THIS block's private line (no cross-CU line share)
            const unsigned pk = ((unsigned)(t + 1) << 16) | bf16_rne(hval);
            unsigned int* slot =
                ring + (((t & 1) * NBLK + blockIdx.x) << 4) + w;
            asm volatile("global_store_dword %0, %1, off sc0 sc1"
                         :: "v"((unsigned long long)slot), "v"(pk) : "memory");
            out[(size_t)t * HDIM + u] = hval;
        }
        if (t == T_STEPS - 1) break;

        // x[t+2] prefetch (latency absorbed by the poll's vmcnt once)
        {
            const int tn = (t + 2 < T_STEPS) ? (t + 2) : (T_STEPS - 1);
            const float* xp = x + (size_t)tn * HDIM;
#pragma unroll
            for (int i = 0; i < 4; ++i) xn[i] = *(const f32x4*)(xp + 4 * l + 256 * i);
        }
        // gx partials for step t+1 (independent of h_t)
#pragma unroll
        for (int q = 0; q < 4; ++q) {
            float a = 0.f;
#pragma unroll
            for (int i = 0; i < 4; ++i) a += dot4(wih[q * 4 + i], xr[i]);
            gxp[q] = a;
        }

        // wait for h_t: thread tid polls block tid's 16B line (its 4 units)
        {
            const unsigned e = (unsigned)(t + 1);
            const unsigned long long base =
                (unsigned long long)(ring + (((t & 1) * NBLK + tid) << 4));
            u32x4 p;
            for (;;) {
                asm volatile(
                    "global_load_dwordx4 %0, %1, off sc0 sc1\n\t"
                    "s_waitcnt vmcnt(0)"
                    : "=&v"(p)
                    : "v"(base)
                    : "memory");
                if ((p[0] >> 16) == e && (p[1] >> 16) == e &&
                    (p[2] >> 16) == e && (p[3] >> 16) == e) break;
            }
            const int ns = (t + 1) & 1;
            f32x4 hv;
            hv[0] = __uint_as_float(p[0] << 16);
            hv[1] = __uint_as_float(p[1] << 16);
            hv[2] = __uint_as_float(p[2] << 16);
            hv[3] = __uint_as_float(p[3] << 16);
            *(f32x4*)&h_lds[ns][4 * tid] = hv;   // units 4*tid .. 4*tid+3
        }
        __syncthreads();
        {
            const int ns = (t + 1) & 1;
#pragma unroll
            for (int i = 0; i < 4; ++i)
                hr[i] = *(const f32x4*)&h_lds[ns][4 * l + 256 * i];
        }
#pragma unroll
        for (int i = 0; i < 4; ++i) xr[i] = xn[i];
    }
}

extern "C" void kernel_launch(void* const* d_in, const int* in_sizes, int n_in,
                              void* d_out, int out_size, void* d_ws, size_t ws_size,
                              hipStream_t stream)
{
    const float* x    = (const float*)d_in[0];
    const float* W_ih = (const float*)d_in[1];
    const float* W_hh = (const float*)d_in[2];
    const float* b_ih = (const float*)d_in[3];
    const float* b_hh = (const float*)d_in[4];
    const float* h0   = (const float*)d_in[5];
    const float* c0   = (const float*)d_in[6];

    unsigned int* ring = (unsigned int*)d_ws;
    hipMemsetAsync(d_ws, 0, 2 * NBLK * 16 * sizeof(unsigned int), stream);
    lstm_persistent<<<NBLK, NTHR, 0, stream>>>(x, W_ih, W_hh, b_ih, b_hh, h0, c0,
                                               (float*)d_out, ring);
}